// Round 4
// baseline (6629.379 us; speedup 1.0000x reference)
//
#include <hip/hip_runtime.h>

// ---------------------------------------------------------------------------
// FocalAtt (CA mode): B=8, Lq=512, Lk=1024, qd=kd=768, hid=1024, mid=4096,
// H=16, dh=64. Inputs f32, OUTPUTS f32 (reference dtype). bf16 internal
// staging, fp32 accumulate. Workspace ~55.8 MB.
// Outputs: x[8,1024], qq[8,512,1024], kp[8,1024,768], att_out[8,512,1024].
// ---------------------------------------------------------------------------

typedef unsigned short bfr;  // raw bf16 bits

__device__ __forceinline__ float b2f(bfr s) {
  return __uint_as_float(((unsigned int)s) << 16);
}
__device__ __forceinline__ bfr f2b(float f) {
  unsigned int u = __float_as_uint(f);
  u += 0x7fffu + ((u >> 16) & 1u);  // RNE
  return (bfr)(u >> 16);
}

struct __align__(8) us4 { bfr x, y, z, w; };

__device__ __forceinline__ float4 load4f(const float* p) { return *(const float4*)p; }
__device__ __forceinline__ float4 load4f(const bfr* p) {
  us4 u = *(const us4*)p;
  return make_float4(b2f(u.x), b2f(u.y), b2f(u.z), b2f(u.w));
}
__device__ __forceinline__ void store4(float* p, float a, float b, float c, float d) {
  *(float4*)p = make_float4(a, b, c, d);
}
__device__ __forceinline__ void store4(bfr* p, float a, float b, float c, float d) {
  us4 v; v.x = f2b(a); v.y = f2b(b); v.z = f2b(c); v.w = f2b(d);
  *(us4*)p = v;
}

// ---------------------------------------------------------------------------
// Positional encoding: pe[l,2i]=sin(l*div_i), pe[l,2i+1]=cos(l*div_i),
// div_i = exp(2i * (-ln(10000)/768))
// ---------------------------------------------------------------------------
__device__ __forceinline__ float pe_val(int l, int d) {
  float ang = (float)l * expf((float)(d & ~1) * (-9.210340371976184f / 768.0f));
  return (d & 1) ? cosf(ang) : sinf(ang);
}

// one batch of q: qp_b[l,d] = q_b[l,d] + pe(l,d), bf16 out. total = 512*768
__global__ __launch_bounds__(256) void posenc_qb(const float* __restrict__ in,
                                                 bfr* __restrict__ out, int total) {
  int idx = blockIdx.x * 256 + threadIdx.x;
  if (idx >= total) return;
  out[idx] = f2b(in[idx] + pe_val(idx / 768, idx % 768));
}

// all batches of k -> f32 kp (d_out; also the K/V projection input)
__global__ __launch_bounds__(256) void posenc_k(const float* __restrict__ in,
                                                float* __restrict__ outf, int total) {
  int idx = blockIdx.x * 256 + threadIdx.x;
  if (idx >= total) return;
  outf[idx] = in[idx] + pe_val((idx / 768) % 1024, idx % 768);
}

// ---------------------------------------------------------------------------
// Tiled GEMM: C[M,N] = A[M,K] @ W[K,N] + bias, optional relu. fp32 accumulate.
// 128x128 block, BK=8, 256 threads, 8x8 per thread. M%128==0, N%128==0, K%8==0.
// ---------------------------------------------------------------------------
template <typename TA, typename TC>
__global__ __launch_bounds__(256) void sgemm_bias(const TA* __restrict__ A,
                                                  const float* __restrict__ W,
                                                  const float* __restrict__ bias,
                                                  TC* __restrict__ C,
                                                  int N, int K, int relu) {
  __shared__ __align__(16) float As[8][132];  // transposed A tile [k][m]
  __shared__ __align__(16) float Bs[8][136];  // [k][n]
  const int tid = threadIdx.x;
  const int bcol = blockIdx.x, brow = blockIdx.y;
  const TA* Ab = A + (size_t)brow * 128 * K;
  const float* Wb = W + (size_t)bcol * 128;
  const int a_r = tid >> 1, a_c = (tid & 1) * 4;
  const int b_r = tid >> 5, b_c = (tid & 31) * 4;
  const int tr = (tid >> 4) * 8, tc = (tid & 15) * 8;
  float acc[8][8] = {};
  for (int k0 = 0; k0 < K; k0 += 8) {
    float4 av = load4f(Ab + (size_t)a_r * K + (k0 + a_c));
    As[a_c + 0][a_r] = av.x; As[a_c + 1][a_r] = av.y;
    As[a_c + 2][a_r] = av.z; As[a_c + 3][a_r] = av.w;
    float4 bv = load4f(Wb + (size_t)(k0 + b_r) * N + b_c);
    *(float4*)&Bs[b_r][b_c] = bv;
    __syncthreads();
#pragma unroll
    for (int kk = 0; kk < 8; ++kk) {
      float ar[8], br[8];
#pragma unroll
      for (int i = 0; i < 8; i++) ar[i] = As[kk][tr + i];
#pragma unroll
      for (int j = 0; j < 8; j++) br[j] = Bs[kk][tc + j];
#pragma unroll
      for (int i = 0; i < 8; i++)
#pragma unroll
        for (int j = 0; j < 8; j++) acc[i][j] = fmaf(ar[i], br[j], acc[i][j]);
    }
    __syncthreads();
  }
#pragma unroll
  for (int i = 0; i < 8; i++) {
    size_t r = (size_t)brow * 128 + tr + i;
#pragma unroll
    for (int j = 0; j < 8; j += 4) {
      int c = bcol * 128 + tc + j;
      float o0 = acc[i][j + 0] + bias[c + 0];
      float o1 = acc[i][j + 1] + bias[c + 1];
      float o2 = acc[i][j + 2] + bias[c + 2];
      float o3 = acc[i][j + 3] + bias[c + 3];
      if (relu) {
        o0 = fmaxf(o0, 0.f); o1 = fmaxf(o1, 0.f);
        o2 = fmaxf(o2, 0.f); o3 = fmaxf(o3, 0.f);
      }
      store4(C + r * N + c, o0, o1, o2, o3);
    }
  }
}

// ---------------------------------------------------------------------------
// Scores (one batch): sc[h,q,k] = dot_64(qh_b[q, h*64+:], kh_b[k, h*64+:]) / 8
// grid (Lk/64, Lq/64, H), 256 threads, 4x4 per thread, dh=64 fully in LDS.
// ---------------------------------------------------------------------------
__global__ __launch_bounds__(256) void score_kernel(const bfr* __restrict__ qhb,
                                                    const bfr* __restrict__ khb,
                                                    bfr* __restrict__ sc) {
  __shared__ __align__(16) float Qs[64][65];
  __shared__ __align__(16) float Ks[64][65];
  const int h = blockIdx.z, q0 = blockIdx.y * 64, k0 = blockIdx.x * 64;
  const bfr* qb = qhb + (size_t)q0 * 1024 + h * 64;
  const bfr* kb = khb + (size_t)k0 * 1024 + h * 64;
  const int tid = threadIdx.x;
#pragma unroll
  for (int i = 0; i < 4; i++) {
    int idx = tid + 256 * i;
    int r = idx >> 4, c = (idx & 15) * 4;
    float4 v = load4f(qb + (size_t)r * 1024 + c);
    Qs[r][c] = v.x; Qs[r][c + 1] = v.y; Qs[r][c + 2] = v.z; Qs[r][c + 3] = v.w;
    float4 w = load4f(kb + (size_t)r * 1024 + c);
    Ks[r][c] = w.x; Ks[r][c + 1] = w.y; Ks[r][c + 2] = w.z; Ks[r][c + 3] = w.w;
  }
  __syncthreads();
  const int tq = (tid >> 4) * 4, tk = (tid & 15) * 4;
  float acc[4][4] = {};
#pragma unroll 8
  for (int d = 0; d < 64; d++) {
    float qr[4], kr[4];
#pragma unroll
    for (int i = 0; i < 4; i++) qr[i] = Qs[tq + i][d];
#pragma unroll
    for (int j = 0; j < 4; j++) kr[j] = Ks[tk + j][d];
#pragma unroll
    for (int i = 0; i < 4; i++)
#pragma unroll
      for (int j = 0; j < 4; j++) acc[i][j] = fmaf(qr[i], kr[j], acc[i][j]);
  }
#pragma unroll
  for (int i = 0; i < 4; i++) {
    bfr* out = sc + ((size_t)h * 512 + q0 + tq + i) * 1024 + k0 + tk;
    store4(out, acc[i][0] * 0.125f, acc[i][1] * 0.125f,
                acc[i][2] * 0.125f, acc[i][3] * 0.125f);
  }
}

// att_out_b[q,k] = sum_h relu(sc[h,q,k]) / 16   (pre-softmax sc), f32 out
__global__ __launch_bounds__(256) void attout_kernel(const bfr* __restrict__ sc,
                                                     float* __restrict__ out) {
  int idx = blockIdx.x * 256 + threadIdx.x;  // < 512*1024
  float s = 0.f;
#pragma unroll
  for (int h = 0; h < 16; h++) s += fmaxf(b2f(sc[(size_t)h * 524288 + idx]), 0.f);
  out[idx] = s * (1.0f / 16.0f);
}

// in-place row softmax over 1024 bf16 (rows = H*Lq = 8192 per batch)
__global__ __launch_bounds__(256) void softmax_kernel(bfr* __restrict__ sc) {
  __shared__ float sm[4];
  const size_t row = blockIdx.x;
  us4* p = (us4*)(sc + row * 1024);
  const int tid = threadIdx.x;
  us4 raw = p[tid];
  float v0 = b2f(raw.x), v1 = b2f(raw.y), v2 = b2f(raw.z), v3 = b2f(raw.w);
  float m = fmaxf(fmaxf(v0, v1), fmaxf(v2, v3));
  for (int o = 32; o; o >>= 1) m = fmaxf(m, __shfl_down(m, o, 64));
  if ((tid & 63) == 0) sm[tid >> 6] = m;
  __syncthreads();
  m = fmaxf(fmaxf(sm[0], sm[1]), fmaxf(sm[2], sm[3]));
  v0 = expf(v0 - m); v1 = expf(v1 - m); v2 = expf(v2 - m); v3 = expf(v3 - m);
  float s = v0 + v1 + v2 + v3;
  __syncthreads();
  for (int o = 32; o; o >>= 1) s += __shfl_down(s, o, 64);
  if ((tid & 63) == 0) sm[tid >> 6] = s;
  __syncthreads();
  s = sm[0] + sm[1] + sm[2] + sm[3];
  float inv = 1.0f / s;
  raw.x = f2b(v0 * inv); raw.y = f2b(v1 * inv);
  raw.z = f2b(v2 * inv); raw.w = f2b(v3 * inv);
  p[tid] = raw;
}

// ---------------------------------------------------------------------------
// atp_b[q, h*64+d] = sum_k att[h,q,k] * v1_b[k, h*64+d]
// u_b [q, h*64+d] = sum_k att[h,q,k] * v0_b[k, h*64+d]
// grid (Lq/64, H), 256 threads, 4x4 per thread of a 64x64 tile, K in 32-chunks.
// ---------------------------------------------------------------------------
__global__ __launch_bounds__(256) void attv_kernel(const bfr* __restrict__ att,
                                                   const bfr* __restrict__ v1,
                                                   const bfr* __restrict__ v0,
                                                   bfr* __restrict__ atp,
                                                   bfr* __restrict__ u) {
  __shared__ __align__(16) float As[64][33];
  __shared__ __align__(16) float B1s[32][65];
  __shared__ __align__(16) float B2s[32][65];
  const int h = blockIdx.y, q0 = blockIdx.x * 64;
  const int tid = threadIdx.x;
  const bfr* attb = att + ((size_t)h * 512 + q0) * 1024;
  const bfr* v1b = v1 + h * 64;
  const bfr* v0b = v0 + h * 64;
  float acc1[4][4] = {}, acc2[4][4] = {};
  const int tq = (tid >> 4) * 4, td = (tid & 15) * 4;
  for (int k0 = 0; k0 < 1024; k0 += 32) {
#pragma unroll
    for (int i = 0; i < 2; i++) {
      int idx = tid + 256 * i;
      int r = idx >> 3, c = (idx & 7) * 4;
      float4 a4 = load4f(attb + (size_t)r * 1024 + k0 + c);
      As[r][c] = a4.x; As[r][c + 1] = a4.y; As[r][c + 2] = a4.z; As[r][c + 3] = a4.w;
      int r2 = idx >> 4, c2 = (idx & 15) * 4;
      float4 b4 = load4f(v1b + (size_t)(k0 + r2) * 1024 + c2);
      B1s[r2][c2] = b4.x; B1s[r2][c2 + 1] = b4.y;
      B1s[r2][c2 + 2] = b4.z; B1s[r2][c2 + 3] = b4.w;
      float4 c4 = load4f(v0b + (size_t)(k0 + r2) * 1024 + c2);
      B2s[r2][c2] = c4.x; B2s[r2][c2 + 1] = c4.y;
      B2s[r2][c2 + 2] = c4.z; B2s[r2][c2 + 3] = c4.w;
    }
    __syncthreads();
#pragma unroll
    for (int kk = 0; kk < 32; kk++) {
      float a[4], b1r[4], b2r[4];
#pragma unroll
      for (int i = 0; i < 4; i++) a[i] = As[tq + i][kk];
#pragma unroll
      for (int j = 0; j < 4; j++) { b1r[j] = B1s[kk][td + j]; b2r[j] = B2s[kk][td + j]; }
#pragma unroll
      for (int i = 0; i < 4; i++)
#pragma unroll
        for (int j = 0; j < 4; j++) {
          acc1[i][j] = fmaf(a[i], b1r[j], acc1[i][j]);
          acc2[i][j] = fmaf(a[i], b2r[j], acc2[i][j]);
        }
    }
    __syncthreads();
  }
  bfr* o1 = atp + (size_t)q0 * 1024 + h * 64;
  bfr* o2 = u + (size_t)q0 * 1024 + h * 64;
#pragma unroll
  for (int i = 0; i < 4; i++) {
    store4(o1 + (size_t)(tq + i) * 1024 + td, acc1[i][0], acc1[i][1], acc1[i][2], acc1[i][3]);
    store4(o2 + (size_t)(tq + i) * 1024 + td, acc2[i][0], acc2[i][1], acc2[i][2], acc2[i][3]);
  }
}

// xpre[b,c] += sum over 64 rows of q0p[b,v,c]*u[b,v,c]   (atomic partial)
__global__ __launch_bounds__(256) void xpre_kernel(const bfr* __restrict__ q0p,
                                                   const bfr* __restrict__ u,
                                                   float* __restrict__ xpre) {
  const int c = blockIdx.x * 256 + threadIdx.x;
  const int b = blockIdx.z, r0 = blockIdx.y * 64;
  const bfr* qp = q0p + ((size_t)b * 512 + r0) * 1024 + c;
  const bfr* up = u + ((size_t)b * 512 + r0) * 1024 + c;
  float s = 0.f;
#pragma unroll 8
  for (int r = 0; r < 64; r++)
    s = fmaf(b2f(qp[(size_t)r * 1024]), b2f(up[(size_t)r * 1024]), s);
  atomicAdd(&xpre[b * 1024 + c], s);
}

// torch_ln over rows of 1024: a*(x-mean)/(sqrt(var_unbiased)+1e-6)+b, X (+Y)
template <typename TX, typename TY, typename OT>
__global__ __launch_bounds__(256) void ln_kernel(const TX* __restrict__ X,
                                                 const TY* __restrict__ Y,
                                                 const float* __restrict__ ga,
                                                 const float* __restrict__ be,
                                                 OT* __restrict__ out) {
  __shared__ float sm[4];
  const size_t row = blockIdx.x;
  const int tid = threadIdx.x;
  float4 v = load4f(X + row * 1024 + tid * 4);
  if (Y) {
    float4 w = load4f(Y + row * 1024 + tid * 4);
    v.x += w.x; v.y += w.y; v.z += w.z; v.w += w.w;
  }
  float s = v.x + v.y + v.z + v.w;
  for (int o = 32; o; o >>= 1) s += __shfl_down(s, o, 64);
  if ((tid & 63) == 0) sm[tid >> 6] = s;
  __syncthreads();
  s = sm[0] + sm[1] + sm[2] + sm[3];
  float mean = s * (1.0f / 1024.0f);
  float d0 = v.x - mean, d1 = v.y - mean, d2 = v.z - mean, d3 = v.w - mean;
  float q = d0 * d0 + d1 * d1 + d2 * d2 + d3 * d3;
  __syncthreads();
  for (int o = 32; o; o >>= 1) q += __shfl_down(q, o, 64);
  if ((tid & 63) == 0) sm[tid >> 6] = q;
  __syncthreads();
  q = sm[0] + sm[1] + sm[2] + sm[3];
  float rs = 1.0f / (sqrtf(q * (1.0f / 1023.0f)) + 1e-6f);
  float4 g = *(const float4*)(ga + tid * 4);
  float4 bb = *(const float4*)(be + tid * 4);
  store4(out + row * 1024 + tid * 4,
         g.x * d0 * rs + bb.x, g.y * d1 * rs + bb.y,
         g.z * d2 * rs + bb.z, g.w * d3 * rs + bb.w);
}

// ---------------------------------------------------------------------------
extern "C" void kernel_launch(void* const* d_in, const int* in_sizes, int n_in,
                              void* d_out, int out_size, void* d_ws, size_t ws_size,
                              hipStream_t stream) {
  (void)in_sizes; (void)n_in; (void)out_size; (void)ws_size;
  const float* q   = (const float*)d_in[0];
  const float* k   = (const float*)d_in[1];
  const float* Wq  = (const float*)d_in[2];
  const float* bq  = (const float*)d_in[3];
  const float* Wk  = (const float*)d_in[4];
  const float* bk  = (const float*)d_in[5];
  const float* Wv  = (const float*)d_in[6];
  const float* bv  = (const float*)d_in[7];
  const float* Wv0 = (const float*)d_in[8];
  const float* bv0 = (const float*)d_in[9];
  const float* Wq0 = (const float*)d_in[10];
  const float* bq0 = (const float*)d_in[11];
  const float* nqa = (const float*)d_in[12];
  const float* nqb = (const float*)d_in[13];
  const float* nxa = (const float*)d_in[14];
  const float* nxb = (const float*)d_in[15];
  const float* W1  = (const float*)d_in[16];
  const float* b1  = (const float*)d_in[17];
  const float* W2  = (const float*)d_in[18];
  const float* b2  = (const float*)d_in[19];
  const float* nsa = (const float*)d_in[20];
  const float* nsb = (const float*)d_in[21];

  float* out = (float*)d_out;
  float* x_out  = out;                       // 8,192
  float* qq_out = out + 8192;                // 4,194,304
  float* kp_out = out + 4202496;             // 6,291,456
  float* ao_out = out + 10493952;            // 4,194,304

  char* base = (char*)d_ws;
  bfr* q0p   = (bfr*)(base + 0);            //  8,388,608  [4096,1024]
  bfr* atp   = (bfr*)(base + 8388608);      //  8,388,608  [4096,1024]
  bfr* u     = (bfr*)(base + 16777216);     //  8,388,608  [4096,1024]
  bfr* sc    = (bfr*)(base + 25165824);     // 16,777,216  [16,512,1024] per batch
  bfr* khb   = (bfr*)(base + 41943040);     //  2,097,152  [1024,1024] per batch
  bfr* v1b   = (bfr*)(base + 44040192);     //  2,097,152
  bfr* v0b   = (bfr*)(base + 46137344);     //  2,097,152
  bfr* qhb   = (bfr*)(base + 48234496);     //  1,048,576  [512,1024] per batch
  bfr* qpb   = (bfr*)(base + 49283072);     //    786,432  [512,768] per batch
  float* xpre = (float*)(base + 50069504);  //     32,768  [8,1024] f32
  bfr* atl   = (bfr*)(base + 50102272);     //  8,388,608  -> ends 58,490,880
  // overlays (dead regions at FFN time):
  bfr* ff1   = (bfr*)(base + 0);            // 33,554,432  [4096,4096] over q0p/atp/u/sc-head
  bfr* ff2   = (bfr*)(base + 33554432);     //  8,388,608  [4096,1024] over sc-tail
  // peak footprint: 58,490,880 B (~55.8 MB)

  // kp = k + PE, f32 straight to d_out (also the K/V projection input)
  posenc_k<<<24576, 256, 0, stream>>>(k, kp_out, 6291456);

  // q0p = q @ Wq0 + bq0 (full batch)
  sgemm_bias<float, bfr><<<dim3(8, 32), 256, 0, stream>>>(q, Wq0, bq0, q0p, 1024, 768, 0);

  // per-batch attention pipeline
  for (int b = 0; b < 8; b++) {
    const float* q_b = q + (size_t)b * 512 * 768;
    const float* kp_b = kp_out + (size_t)b * 1024 * 768;
    posenc_qb<<<1536, 256, 0, stream>>>(q_b, qpb, 393216);
    sgemm_bias<bfr, bfr><<<dim3(8, 4), 256, 0, stream>>>(qpb, Wq, bq, qhb, 1024, 768, 0);
    sgemm_bias<float, bfr><<<dim3(8, 8), 256, 0, stream>>>(kp_b, Wk, bk, khb, 1024, 768, 0);
    sgemm_bias<float, bfr><<<dim3(8, 8), 256, 0, stream>>>(kp_b, Wv, bv, v1b, 1024, 768, 0);
    sgemm_bias<float, bfr><<<dim3(8, 8), 256, 0, stream>>>(kp_b, Wv0, bv0, v0b, 1024, 768, 0);
    score_kernel<<<dim3(16, 8, 16), 256, 0, stream>>>(qhb, khb, sc);
    attout_kernel<<<2048, 256, 0, stream>>>(sc, ao_out + (size_t)b * 524288);
    softmax_kernel<<<8192, 256, 0, stream>>>(sc);
    attv_kernel<<<dim3(8, 16), 256, 0, stream>>>(sc, v1b, v0b,
                                                 atp + (size_t)b * 524288,
                                                 u + (size_t)b * 524288);
  }

  // bilinear contraction + LN -> x (f32 out)
  hipMemsetAsync(xpre, 0, 8192 * sizeof(float), stream);
  xpre_kernel<<<dim3(4, 8, 8), 256, 0, stream>>>(q0p, u, xpre);
  ln_kernel<float, float, float><<<8, 256, 0, stream>>>(xpre, (const float*)nullptr,
                                                        nxa, nxb, x_out);

  // atted = LN(q0p + atted_pre)
  ln_kernel<bfr, bfr, bfr><<<4096, 256, 0, stream>>>(q0p, atp, nqa, nqb, atl);

  // FFN + residual LN -> qq (f32 out)
  sgemm_bias<bfr, bfr><<<dim3(32, 32), 256, 0, stream>>>(atl, W1, b1, ff1, 4096, 1024, 1);
  sgemm_bias<bfr, bfr><<<dim3(8, 32), 256, 0, stream>>>(ff1, W2, b2, ff2, 1024, 4096, 0);
  ln_kernel<bfr, bfr, float><<<4096, 256, 0, stream>>>(atl, ff2, nsa, nsb, qq_out);
}

// Round 5
// 2093.865 us; speedup vs baseline: 3.1661x; 3.1661x over previous
//
#include <hip/hip_runtime.h>

// ---------------------------------------------------------------------------
// FocalAtt (CA mode): B=8, Lq=512, Lk=1024, qd=kd=768, hid=1024, mid=4096,
// H=16, dh=64. Inputs f32, outputs f32. bf16 MFMA GEMMs (16x16x32), fp32 acc.
// Workspace peak 58,241,024 B (< known-good 58,490,880).
// ---------------------------------------------------------------------------

typedef unsigned short bfr;  // raw bf16 bits
using short8 = __attribute__((ext_vector_type(8))) short;
using f32x4  = __attribute__((ext_vector_type(4))) float;

__device__ __forceinline__ float b2f(bfr s) {
  return __uint_as_float(((unsigned int)s) << 16);
}
__device__ __forceinline__ bfr f2b(float f) {
  unsigned int u = __float_as_uint(f);
  u += 0x7fffu + ((u >> 16) & 1u);  // RNE
  return (bfr)(u >> 16);
}

struct __align__(8) us4 { bfr x, y, z, w; };

__device__ __forceinline__ float4 load4f(const float* p) { return *(const float4*)p; }
__device__ __forceinline__ float4 load4f(const bfr* p) {
  us4 u = *(const us4*)p;
  return make_float4(b2f(u.x), b2f(u.y), b2f(u.z), b2f(u.w));
}
__device__ __forceinline__ void store4(float* p, float a, float b, float c, float d) {
  *(float4*)p = make_float4(a, b, c, d);
}
__device__ __forceinline__ void store4(bfr* p, float a, float b, float c, float d) {
  us4 v; v.x = f2b(a); v.y = f2b(b); v.z = f2b(c); v.w = f2b(d);
  *(us4*)p = v;
}

// ---------------------------------------------------------------------------
// Positional encoding
// ---------------------------------------------------------------------------
__device__ __forceinline__ float pe_val(int l, int d) {
  float ang = (float)l * expf((float)(d & ~1) * (-9.210340371976184f / 768.0f));
  return (d & 1) ? cosf(ang) : sinf(ang);
}

// k + PE -> f32 kp (d_out; also K/V projection A-input). total = 8*1024*768
__global__ __launch_bounds__(256) void posenc_k(const float* __restrict__ in,
                                                float* __restrict__ outf, int total) {
  int idx = blockIdx.x * 256 + threadIdx.x;
  if (idx >= total) return;
  outf[idx] = in[idx] + pe_val((idx / 768) % 1024, idx % 768);
}

// q + PE -> bf16 qp_all [4096,768]
__global__ __launch_bounds__(256) void posenc_q_all(const float* __restrict__ in,
                                                    bfr* __restrict__ out, int total) {
  int idx = blockIdx.x * 256 + threadIdx.x;
  if (idx >= total) return;
  out[idx] = f2b(in[idx] + pe_val((idx / 768) % 512, idx % 768));
}

// ---------------------------------------------------------------------------
// Weight transpose: src f32 [rows, cols] (row stride ld) -> dst bf16 [cols, rows]
// grid (cols/32, rows/32), 256 threads.
// ---------------------------------------------------------------------------
__global__ __launch_bounds__(256) void transpose_w(const float* __restrict__ src,
                                                   bfr* __restrict__ dst,
                                                   int rows, int cols, int ld) {
  __shared__ float t[32][33];
  const int bc = blockIdx.x * 32, br = blockIdx.y * 32;
  const int tx = threadIdx.x & 31, ty = threadIdx.x >> 5;  // ty 0..7
#pragma unroll
  for (int i = 0; i < 4; i++)
    t[ty + i * 8][tx] = src[(size_t)(br + ty + i * 8) * ld + bc + tx];
  __syncthreads();
#pragma unroll
  for (int i = 0; i < 4; i++)
    dst[(size_t)(bc + ty + i * 8) * rows + br + tx] = f2b(t[tx][ty + i * 8]);
}

__global__ __launch_bounds__(256) void concat_bias(const float* __restrict__ a,
                                                   const float* __restrict__ b,
                                                   const float* __restrict__ c,
                                                   float* __restrict__ o) {
  int i = blockIdx.x * 256 + threadIdx.x;  // < 3072
  o[i] = i < 1024 ? a[i] : (i < 2048 ? b[i - 1024] : c[i - 2048]);
}

// ---------------------------------------------------------------------------
// MFMA GEMM: C[M,N] = A[M,K] @ B[K,N] (+bias, relu, accum). B passed as
// BT[N,K] bf16 (pre-transposed). 128x128 block, 256 thr = 4 waves, each wave
// 64x64 via 4x4 of v_mfma_f32_16x16x32_bf16. BK=32. All dims %128==0, K%32==0.
// A-frag: lane holds A[m=lane&15][k=(lane>>4)*8+j]; D: row=(lane>>4)*4+r,
// col=lane&15 (measured m89/m91 layouts).
// ---------------------------------------------------------------------------
__device__ __forceinline__ void stage16(const bfr* __restrict__ s, bfr* d) {
  *(short8*)d = *(const short8*)s;
  *(short8*)(d + 8) = *(const short8*)(s + 8);
}
__device__ __forceinline__ void stage16(const float* __restrict__ s, bfr* d) {
  bfr tmp[16];
#pragma unroll
  for (int i = 0; i < 16; i += 4) {
    float4 v = *(const float4*)(s + i);
    tmp[i] = f2b(v.x); tmp[i + 1] = f2b(v.y);
    tmp[i + 2] = f2b(v.z); tmp[i + 3] = f2b(v.w);
  }
  *(short8*)d = *(short8*)&tmp[0];
  *(short8*)(d + 8) = *(short8*)&tmp[8];
}

template <typename TA, typename TC>
__global__ __launch_bounds__(256) void mgemm(const TA* __restrict__ A,
                                             const bfr* __restrict__ BT,
                                             const float* __restrict__ bias,
                                             TC* __restrict__ C,
                                             int K, int ldc, int relu, int accum) {
  __shared__ bfr As[128][40];  // row stride 80 B = 20 banks (2-way max, free)
  __shared__ bfr Bs[128][40];
  const int tid = threadIdx.x;
  const int n0 = blockIdx.x * 128, m0 = blockIdx.y * 128;
  const int lane = tid & 63;
  const int wm = ((tid >> 6) & 1) * 64, wn = (tid >> 7) * 64;
  const int sr = tid >> 1, sc16 = (tid & 1) * 16;
  const int fr = lane & 15, fc = (lane >> 4) * 8;
  f32x4 acc[4][4];
#pragma unroll
  for (int i = 0; i < 4; i++)
#pragma unroll
    for (int j = 0; j < 4; j++) acc[i][j] = (f32x4){0.f, 0.f, 0.f, 0.f};
  for (int k0 = 0; k0 < K; k0 += 32) {
    stage16(A + (size_t)(m0 + sr) * K + k0 + sc16, &As[sr][sc16]);
    stage16(BT + (size_t)(n0 + sr) * K + k0 + sc16, &Bs[sr][sc16]);
    __syncthreads();
    short8 af[4], bf[4];
#pragma unroll
    for (int t = 0; t < 4; t++) af[t] = *(const short8*)&As[wm + t * 16 + fr][fc];
#pragma unroll
    for (int t = 0; t < 4; t++) bf[t] = *(const short8*)&Bs[wn + t * 16 + fr][fc];
#pragma unroll
    for (int i = 0; i < 4; i++)
#pragma unroll
      for (int j = 0; j < 4; j++)
        acc[i][j] = __builtin_amdgcn_mfma_f32_16x16x32_bf16(af[i], bf[j], acc[i][j], 0, 0, 0);
    __syncthreads();
  }
  const int col0 = n0 + wn + fr;
  const int row0 = m0 + wm + (lane >> 4) * 4;
  float bsv[4];
#pragma unroll
  for (int j = 0; j < 4; j++) bsv[j] = bias ? bias[col0 + j * 16] : 0.f;
#pragma unroll
  for (int i = 0; i < 4; i++) {
#pragma unroll
    for (int j = 0; j < 4; j++) {
      const int col = col0 + j * 16;
#pragma unroll
      for (int r = 0; r < 4; r++) {
        const int row = row0 + i * 16 + r;
        float v = acc[i][j][r] + bsv[j];
        if (relu) v = fmaxf(v, 0.f);
        size_t idx = (size_t)row * ldc + col;
        if constexpr (sizeof(TC) == 2) {
          C[idx] = f2b(v);
        } else {
          if (accum) C[idx] += v; else C[idx] = v;
        }
      }
    }
  }
}

// ---------------------------------------------------------------------------
// Scores (one batch): sc[h,q,k] = dot_64(qh_b[q,h*64+:], khv[k,h*64+:]) / 8
// khv row stride 3072 (cols 0..1023 = kh). grid (16,8,16), 256 thr, 4x4/thr.
// ---------------------------------------------------------------------------
__global__ __launch_bounds__(256) void score_kernel(const bfr* __restrict__ qhb,
                                                    const bfr* __restrict__ khv,
                                                    bfr* __restrict__ sc) {
  __shared__ __align__(16) float Qs[64][65];
  __shared__ __align__(16) float Ks[64][65];
  const int h = blockIdx.z, q0 = blockIdx.y * 64, k0 = blockIdx.x * 64;
  const bfr* qb = qhb + (size_t)q0 * 1024 + h * 64;
  const bfr* kb = khv + (size_t)k0 * 3072 + h * 64;
  const int tid = threadIdx.x;
#pragma unroll
  for (int i = 0; i < 4; i++) {
    int idx = tid + 256 * i;
    int r = idx >> 4, c = (idx & 15) * 4;
    float4 v = load4f(qb + (size_t)r * 1024 + c);
    Qs[r][c] = v.x; Qs[r][c + 1] = v.y; Qs[r][c + 2] = v.z; Qs[r][c + 3] = v.w;
    float4 w = load4f(kb + (size_t)r * 3072 + c);
    Ks[r][c] = w.x; Ks[r][c + 1] = w.y; Ks[r][c + 2] = w.z; Ks[r][c + 3] = w.w;
  }
  __syncthreads();
  const int tq = (tid >> 4) * 4, tk = (tid & 15) * 4;
  float acc[4][4] = {};
#pragma unroll 8
  for (int d = 0; d < 64; d++) {
    float qr[4], kr[4];
#pragma unroll
    for (int i = 0; i < 4; i++) qr[i] = Qs[tq + i][d];
#pragma unroll
    for (int j = 0; j < 4; j++) kr[j] = Ks[tk + j][d];
#pragma unroll
    for (int i = 0; i < 4; i++)
#pragma unroll
      for (int j = 0; j < 4; j++) acc[i][j] = fmaf(qr[i], kr[j], acc[i][j]);
  }
#pragma unroll
  for (int i = 0; i < 4; i++) {
    bfr* out = sc + ((size_t)h * 512 + q0 + tq + i) * 1024 + k0 + tk;
    store4(out, acc[i][0] * 0.125f, acc[i][1] * 0.125f,
                acc[i][2] * 0.125f, acc[i][3] * 0.125f);
  }
}

// att_out_b[q,k] = sum_h relu(sc[h,q,k]) / 16 (pre-softmax), f32 out
__global__ __launch_bounds__(256) void attout_kernel(const bfr* __restrict__ sc,
                                                     float* __restrict__ out) {
  int idx = blockIdx.x * 256 + threadIdx.x;  // < 512*1024
  float s = 0.f;
#pragma unroll
  for (int h = 0; h < 16; h++) s += fmaxf(b2f(sc[(size_t)h * 524288 + idx]), 0.f);
  out[idx] = s * (1.0f / 16.0f);
}

// in-place row softmax over 1024 bf16 (rows = 8192 per batch)
__global__ __launch_bounds__(256) void softmax_kernel(bfr* __restrict__ sc) {
  __shared__ float sm[4];
  const size_t row = blockIdx.x;
  us4* p = (us4*)(sc + row * 1024);
  const int tid = threadIdx.x;
  us4 raw = p[tid];
  float v0 = b2f(raw.x), v1 = b2f(raw.y), v2 = b2f(raw.z), v3 = b2f(raw.w);
  float m = fmaxf(fmaxf(v0, v1), fmaxf(v2, v3));
  for (int o = 32; o; o >>= 1) m = fmaxf(m, __shfl_down(m, o, 64));
  if ((tid & 63) == 0) sm[tid >> 6] = m;
  __syncthreads();
  m = fmaxf(fmaxf(sm[0], sm[1]), fmaxf(sm[2], sm[3]));
  v0 = expf(v0 - m); v1 = expf(v1 - m); v2 = expf(v2 - m); v3 = expf(v3 - m);
  float s = v0 + v1 + v2 + v3;
  __syncthreads();
  for (int o = 32; o; o >>= 1) s += __shfl_down(s, o, 64);
  if ((tid & 63) == 0) sm[tid >> 6] = s;
  __syncthreads();
  s = sm[0] + sm[1] + sm[2] + sm[3];
  float inv = 1.0f / s;
  raw.x = f2b(v0 * inv); raw.y = f2b(v1 * inv);
  raw.z = f2b(v2 * inv); raw.w = f2b(v3 * inv);
  p[tid] = raw;
}

// ---------------------------------------------------------------------------
// atp_b[q,h*64+d] = sum_k att[h,q,k]*v1[k,h*64+d]; u_b same with v0.
// v1 = khv cols 1024.., v0 = cols 2048.., row stride 3072. grid (8,16).
// ---------------------------------------------------------------------------
__global__ __launch_bounds__(256) void attv_kernel(const bfr* __restrict__ att,
                                                   const bfr* __restrict__ khv,
                                                   bfr* __restrict__ atp,
                                                   bfr* __restrict__ u) {
  __shared__ __align__(16) float As[64][33];
  __shared__ __align__(16) float B1s[32][65];
  __shared__ __align__(16) float B2s[32][65];
  const int h = blockIdx.y, q0 = blockIdx.x * 64;
  const int tid = threadIdx.x;
  const bfr* attb = att + ((size_t)h * 512 + q0) * 1024;
  const bfr* v1b = khv + 1024 + h * 64;
  const bfr* v0b = khv + 2048 + h * 64;
  float acc1[4][4] = {}, acc2[4][4] = {};
  const int tq = (tid >> 4) * 4, td = (tid & 15) * 4;
  for (int k0 = 0; k0 < 1024; k0 += 32) {
#pragma unroll
    for (int i = 0; i < 2; i++) {
      int idx = tid + 256 * i;
      int r = idx >> 3, c = (idx & 7) * 4;
      float4 a4 = load4f(attb + (size_t)r * 1024 + k0 + c);
      As[r][c] = a4.x; As[r][c + 1] = a4.y; As[r][c + 2] = a4.z; As[r][c + 3] = a4.w;
      int r2 = idx >> 4, c2 = (idx & 15) * 4;
      float4 b4 = load4f(v1b + (size_t)(k0 + r2) * 3072 + c2);
      B1s[r2][c2] = b4.x; B1s[r2][c2 + 1] = b4.y;
      B1s[r2][c2 + 2] = b4.z; B1s[r2][c2 + 3] = b4.w;
      float4 c4 = load4f(v0b + (size_t)(k0 + r2) * 3072 + c2);
      B2s[r2][c2] = c4.x; B2s[r2][c2 + 1] = c4.y;
      B2s[r2][c2 + 2] = c4.z; B2s[r2][c2 + 3] = c4.w;
    }
    __syncthreads();
#pragma unroll
    for (int kk = 0; kk < 32; kk++) {
      float a[4], b1r[4], b2r[4];
#pragma unroll
      for (int i = 0; i < 4; i++) a[i] = As[tq + i][kk];
#pragma unroll
      for (int j = 0; j < 4; j++) { b1r[j] = B1s[kk][td + j]; b2r[j] = B2s[kk][td + j]; }
#pragma unroll
      for (int i = 0; i < 4; i++)
#pragma unroll
        for (int j = 0; j < 4; j++) {
          acc1[i][j] = fmaf(a[i], b1r[j], acc1[i][j]);
          acc2[i][j] = fmaf(a[i], b2r[j], acc2[i][j]);
        }
    }
    __syncthreads();
  }
  bfr* o1 = atp + (size_t)q0 * 1024 + h * 64;
  bfr* o2 = u + (size_t)q0 * 1024 + h * 64;
#pragma unroll
  for (int i = 0; i < 4; i++) {
    store4(o1 + (size_t)(tq + i) * 1024 + td, acc1[i][0], acc1[i][1], acc1[i][2], acc1[i][3]);
    store4(o2 + (size_t)(tq + i) * 1024 + td, acc2[i][0], acc2[i][1], acc2[i][2], acc2[i][3]);
  }
}

// xpre_b[c] += sum over 64 rows of q0p_b[v,c]*u_b[v,c] (per batch), grid (4,8)
__global__ __launch_bounds__(256) void xpre_kernel(const bfr* __restrict__ q0p,
                                                   const bfr* __restrict__ u,
                                                   float* __restrict__ xpre) {
  const int c = blockIdx.x * 256 + threadIdx.x;
  const int r0 = blockIdx.y * 64;
  const bfr* qp = q0p + (size_t)r0 * 1024 + c;
  const bfr* up = u + (size_t)r0 * 1024 + c;
  float s = 0.f;
#pragma unroll 8
  for (int r = 0; r < 64; r++)
    s = fmaf(b2f(qp[(size_t)r * 1024]), b2f(up[(size_t)r * 1024]), s);
  atomicAdd(&xpre[c], s);
}

// torch_ln over rows of 1024: a*(x-mean)/(sqrt(var_unbiased)+1e-6)+b, X (+Y)
template <typename TX, typename TY, typename OT>
__global__ __launch_bounds__(256) void ln_kernel(const TX* __restrict__ X,
                                                 const TY* __restrict__ Y,
                                                 const float* __restrict__ ga,
                                                 const float* __restrict__ be,
                                                 OT* __restrict__ out) {
  __shared__ float sm[4];
  const size_t row = blockIdx.x;
  const int tid = threadIdx.x;
  float4 v = load4f(X + row * 1024 + tid * 4);
  if (Y) {
    float4 w = load4f(Y + row * 1024 + tid * 4);
    v.x += w.x; v.y += w.y; v.z += w.z; v.w += w.w;
  }
  float s = v.x + v.y + v.z + v.w;
  for (int o = 32; o; o >>= 1) s += __shfl_down(s, o, 64);
  if ((tid & 63) == 0) sm[tid >> 6] = s;
  __syncthreads();
  s = sm[0] + sm[1] + sm[2] + sm[3];
  float mean = s * (1.0f / 1024.0f);
  float d0 = v.x - mean, d1 = v.y - mean, d2 = v.z - mean, d3 = v.w - mean;
  float q = d0 * d0 + d1 * d1 + d2 * d2 + d3 * d3;
  __syncthreads();
  for (int o = 32; o; o >>= 1) q += __shfl_down(q, o, 64);
  if ((tid & 63) == 0) sm[tid >> 6] = q;
  __syncthreads();
  q = sm[0] + sm[1] + sm[2] + sm[3];
  float rs = 1.0f / (sqrtf(q * (1.0f / 1023.0f)) + 1e-6f);
  float4 g = *(const float4*)(ga + tid * 4);
  float4 bb = *(const float4*)(be + tid * 4);
  store4(out + row * 1024 + tid * 4,
         g.x * d0 * rs + bb.x, g.y * d1 * rs + bb.y,
         g.z * d2 * rs + bb.z, g.w * d3 * rs + bb.w);
}

// ---------------------------------------------------------------------------
extern "C" void kernel_launch(void* const* d_in, const int* in_sizes, int n_in,
                              void* d_out, int out_size, void* d_ws, size_t ws_size,
                              hipStream_t stream) {
  (void)in_sizes; (void)n_in; (void)out_size; (void)ws_size;
  const float* q   = (const float*)d_in[0];
  const float* k   = (const float*)d_in[1];
  const float* Wq  = (const float*)d_in[2];
  const float* bq  = (const float*)d_in[3];
  const float* Wk  = (const float*)d_in[4];
  const float* bk  = (const float*)d_in[5];
  const float* Wv  = (const float*)d_in[6];
  const float* bv  = (const float*)d_in[7];
  const float* Wv0 = (const float*)d_in[8];
  const float* bv0 = (const float*)d_in[9];
  const float* Wq0 = (const float*)d_in[10];
  const float* bq0 = (const float*)d_in[11];
  const float* nqa = (const float*)d_in[12];
  const float* nqb = (const float*)d_in[13];
  const float* nxa = (const float*)d_in[14];
  const float* nxb = (const float*)d_in[15];
  const float* W1  = (const float*)d_in[16];
  const float* b1  = (const float*)d_in[17];
  const float* W2  = (const float*)d_in[18];
  const float* b2  = (const float*)d_in[19];
  const float* nsa = (const float*)d_in[20];
  const float* nsb = (const float*)d_in[21];

  float* out = (float*)d_out;
  float* x_out  = out;                       // 8,192
  float* qq_out = out + 8192;                // 4,194,304
  float* kp_out = out + 4202496;             // 6,291,456
  float* ao_out = out + 10493952;            // 4,194,304

  char* base = (char*)d_ws;
  // persistent
  bfr* q0p   = (bfr*)(base + 0);            // 8,388,608  [4096,1024]
  bfr* qh    = (bfr*)(base + 8388608);      // 8,388,608  [4096,1024]
  bfr* atl   = (bfr*)(base + 16777216);     // 8,388,608  [4096,1024]
  bfr* WqT   = (bfr*)(base + 25165824);     // 1,572,864  [1024,768]
  bfr* Wq0T  = (bfr*)(base + 26738688);     // 1,572,864
  bfr* WTkv  = (bfr*)(base + 28311552);     // 4,718,592  [3072,768]
  float* bkv  = (float*)(base + 33030144);  //    12,288  [3072]
  float* xpre = (float*)(base + 33042432);  //    32,768  [8,1024]
  char* S = base + 33075200;                // scratch region, 25,165,824 B
  // attention-loop overlay
  bfr* sc    = (bfr*)(S + 0);               // 16,777,216 [16,512,1024]
  bfr* khv   = (bfr*)(S + 16777216);        //  6,291,456 [1024,3072]
  bfr* atpb  = (bfr*)(S + 23068672);        //  1,048,576 [512,1024]
  bfr* ub    = (bfr*)(S + 24117248);        //  1,048,576
  // pre-loop overlay (dead before sc/khv first written)
  bfr* qp_all = (bfr*)(S + 0);              //  6,291,456 [4096,768]
  // FFN-phase overlay (attention buffers dead)
  bfr* W1Tn  = (bfr*)(S + 0);               //  1,048,576 [512,1024]
  bfr* W2Tn  = (bfr*)(S + 1048576);         //  1,048,576 [1024,512]
  bfr* ff1n  = (bfr*)(S + 2097152);         //  4,194,304 [4096,512]
  float* ff2a = (float*)(S + 6291456);      // 16,777,216 [4096,1024] f32
  // peak footprint: 58,241,024 B

  // --- setup ---
  posenc_k<<<24576, 256, 0, stream>>>(k, kp_out, 6291456);
  posenc_q_all<<<12288, 256, 0, stream>>>(q, qp_all, 3145728);
  transpose_w<<<dim3(32, 24), 256, 0, stream>>>(Wq, WqT, 768, 1024, 1024);
  transpose_w<<<dim3(32, 24), 256, 0, stream>>>(Wq0, Wq0T, 768, 1024, 1024);
  transpose_w<<<dim3(32, 24), 256, 0, stream>>>(Wk, WTkv, 768, 1024, 1024);
  transpose_w<<<dim3(32, 24), 256, 0, stream>>>(Wv, WTkv + 786432, 768, 1024, 1024);
  transpose_w<<<dim3(32, 24), 256, 0, stream>>>(Wv0, WTkv + 1572864, 768, 1024, 1024);
  concat_bias<<<12, 256, 0, stream>>>(bk, bv, bv0, bkv);

  // full-batch projections (MFMA)
  mgemm<float, bfr><<<dim3(8, 32), 256, 0, stream>>>(q, Wq0T, bq0, q0p, 768, 1024, 0, 0);
  mgemm<bfr, bfr><<<dim3(8, 32), 256, 0, stream>>>(qp_all, WqT, bq, qh, 768, 1024, 0, 0);
  hipMemsetAsync(xpre, 0, 32768, stream);

  // --- per-batch attention ---
  for (int b = 0; b < 8; b++) {
    mgemm<float, bfr><<<dim3(24, 8), 256, 0, stream>>>(
        kp_out + (size_t)b * 786432, WTkv, bkv, khv, 768, 3072, 0, 0);
    score_kernel<<<dim3(16, 8, 16), 256, 0, stream>>>(qh + (size_t)b * 524288, khv, sc);
    attout_kernel<<<2048, 256, 0, stream>>>(sc, ao_out + (size_t)b * 524288);
    softmax_kernel<<<8192, 256, 0, stream>>>(sc);
    attv_kernel<<<dim3(8, 16), 256, 0, stream>>>(sc, khv, atpb, ub);
    xpre_kernel<<<dim3(4, 8), 256, 0, stream>>>(q0p + (size_t)b * 524288, ub,
                                                xpre + b * 1024);
    ln_kernel<bfr, bfr, bfr><<<512, 256, 0, stream>>>(
        q0p + (size_t)b * 524288, atpb, nqa, nqb, atl + (size_t)b * 524288);
  }

  // x = LN(bilinear)
  ln_kernel<float, float, float><<<8, 256, 0, stream>>>(xpre, (const float*)nullptr,
                                                        nxa, nxb, x_out);

  // --- FFN, K-split into 8 chunks of 512, f32 accumulation ---
  for (int nc = 0; nc < 8; nc++) {
    transpose_w<<<dim3(16, 32), 256, 0, stream>>>(W1 + nc * 512, W1Tn, 1024, 512, 4096);
    transpose_w<<<dim3(32, 16), 256, 0, stream>>>(W2 + (size_t)nc * 512 * 1024, W2Tn,
                                                  512, 1024, 1024);
    mgemm<bfr, bfr><<<dim3(4, 32), 256, 0, stream>>>(atl, W1Tn, b1 + nc * 512, ff1n,
                                                     1024, 512, 1, 0);
    mgemm<bfr, float><<<dim3(8, 32), 256, 0, stream>>>(ff1n, W2Tn,
                                                       nc == 0 ? b2 : nullptr, ff2a,
                                                       512, 1024, 0, nc > 0);
  }
  ln_kernel<bfr, float, float><<<4096, 256, 0, stream>>>(atl, ff2a, nsa, nsb, qq_out);
}